// Round 8
// baseline (399.414 us; speedup 1.0000x reference)
//
#include <hip/hip_runtime.h>

// B=131072, T=16, D=2, H=64. 16 rows/wave, 4 waves/block (R9 shape).
// R13 (from R12 post-mortem): occupancy = floor(512/VGPR) fine-grained; R12's
// 24-wave config was eaten by a ragged 1.6-batch grid. Instead: LDS diet on the
// proven 256-thr block -> 5 blocks/CU (20 waves), even-ish batches (2048/1280).
//  - hbuf∪hidbuf union in one 2304B/wave slot (h dead after a0/a1 reload) -5120
//  - gi_tab float4 -> float2 {w0,w1}; biases hoisted to regs, injected via
//    MFMA C-init (bhn-proven pattern)                                     -1536
//  - ystate LDS -> __shfl from epilogue lanes (yc regs)                   -512
// LDS = 16384+4096+9216+1536 = 31232 B; x5 = 156160 <= 163840.
// launch_bounds(256,3) cap 170 -- NO tight caps (R6/R10/R11 spill lessons).
// Hot-loop numerics identical to R9 (fused single-rcp tail, deferred log).
#define BSZ 131072
#define TT  16
#define RPB 64
#define BLK 256

#define NEG_LOG2E  (-1.4426950408889634f)
#define TWO_LOG2E  2.8853900817779268f

typedef __bf16 bf16x8 __attribute__((ext_vector_type(8)));
typedef float  f32x4  __attribute__((ext_vector_type(4)));

#define MFMA(a,b,c) __builtin_amdgcn_mfma_f32_16x16x32_bf16((a),(b),(c),0,0,0)

static __device__ __forceinline__ float rcp_f(float v){ float r; asm("v_rcp_f32 %0, %1" : "=v"(r) : "v"(v)); return r; }
static __device__ __forceinline__ float exp2_f(float v){ float r; asm("v_exp_f32 %0, %1" : "=v"(r) : "v"(v)); return r; }

__global__ __launch_bounds__(BLK, 3) void flow13(
    const float* __restrict__ x,     // (B,16,2)
    const float* __restrict__ z,     // (B,64)
    const float* __restrict__ W_ih,  // (192,2)
    const float* __restrict__ W_hh,  // (192,64)
    const float* __restrict__ b_ih,  // (192)
    const float* __restrict__ b_hh,  // (192)
    const float* __restrict__ W1,    // (64,32)
    const float* __restrict__ b1,    // (32)
    const float* __restrict__ W2,    // (32,4)
    const float* __restrict__ b2,    // (4)
    float* __restrict__ y_out,       // (B,16,2)
    float* __restrict__ lad_out)     // (B)
{
  // LDS: 16384 + 4096 + 9216 + 1536 = 31232 B  -> 5 blocks/CU
  __shared__ __align__(16) __bf16 whhtab[16*64*8];  // z/n-gate B-frags (pre-scaled)
  __shared__ __align__(16) __bf16 w1tab[4*64*8];    // W1 B-frags
  __shared__ __align__(16) __bf16 ubuf[RPB*72];     // per-wave slot (1152 elem):
                                                    //   h (stride 72) THEN hid (stride 40, cols 32..39 = ls)
  __shared__ __align__(16) float2 giw[192];         // {Wih0, Wih1} pre-scaled

  const int tid  = threadIdx.x;
  const int lane = tid & 63, wave = tid >> 6;
  const int quad = lane >> 4, n16 = lane & 15;
  const int gb   = blockIdx.x * RPB;

  // ---------- one-time staging ----------
  if (tid < 192) {  // giw: pre-scaled W_ih pairs
    const int j = tid;
    const float sc = (j < 128) ? NEG_LOG2E : TWO_LOG2E;
    giw[j] = make_float2(W_ih[2*j]*sc, W_ih[2*j+1]*sc);
  }
  // whhtab: f = (gate-1)*8 + g*2 + kt, gate 1=z (x -log2e), 2=n (x 2log2e)
  #pragma unroll
  for (int i = 0; i < 4; ++i) {
    const int f = i*4 + wave;
    const int gate = 1 + (f >> 3), g = (f >> 1) & 3, kt = f & 1;
    const float sc = (gate == 1) ? NEG_LOG2E : TWO_LOG2E;
    const float* p = W_hh + (size_t)((gate*4 + g)*16 + n16)*64 + kt*32 + quad*8;
    bf16x8 v;
    #pragma unroll
    for (int j = 0; j < 8; ++j) v[j] = (__bf16)(p[j]*sc);
    *(bf16x8*)&whhtab[(f*64 + lane)*8] = v;
  }
  { // w1tab: frag f = c2*2+kt, one per wave (unscaled)
    const int f = wave, c2 = f >> 1, kt = f & 1;
    bf16x8 v;
    #pragma unroll
    for (int j = 0; j < 8; ++j)
      v[j] = (__bf16)W1[(size_t)(kt*32 + quad*8 + j)*32 + c2*16 + n16];
    *(bf16x8*)&w1tab[(f*64 + lane)*8] = v;
  }
  #pragma unroll
  for (int r4 = 0; r4 < 4; ++r4) {  // z -> ubuf h-region (stride 72; slot-equivalent)
    const int row = (tid >> 4) + r4*16, col = (tid & 15)*4;
    const float4 zv = *(const float4*)&z[(size_t)(gb + row)*64 + col];
    ubuf[row*72 + col+0] = (__bf16)zv.x; ubuf[row*72 + col+1] = (__bf16)zv.y;
    ubuf[row*72 + col+2] = (__bf16)zv.z; ubuf[row*72 + col+3] = (__bf16)zv.w;
  }

  // r-gate B-frags in regs (pre-scaled by -log2e): 8 x bf16x8 = 32 VGPR
  bf16x8 Whr[4][2];
  #pragma unroll
  for (int g = 0; g < 4; ++g)
    #pragma unroll
    for (int kt = 0; kt < 2; ++kt) {
      const float* p = W_hh + (size_t)(g*16 + n16)*64 + kt*32 + quad*8;
      bf16x8 v;
      #pragma unroll
      for (int j = 0; j < 8; ++j) v[j] = (__bf16)(p[j]*NEG_LOG2E);
      Whr[g][kt] = v;
    }
  // W2 B-frag in regs (4 VGPR)
  bf16x8 W2f;
  #pragma unroll
  for (int j = 0; j < 8; ++j)
    W2f[j] = (n16 < 4) ? (__bf16)W2[(size_t)(quad*8 + j)*4 + n16] : (__bf16)0.f;

  // h state fp32 C-layout: hst[g][i] = h[quad*4+i][g*16+n16]
  f32x4 hst[4];
  #pragma unroll
  for (int g = 0; g < 4; ++g)
    #pragma unroll
    for (int i = 0; i < 4; ++i)
      hst[g][i] = z[(size_t)(gb + wave*16 + quad*4 + i)*64 + g*16 + n16];
  // hoisted scaled biases (MFMA C-init / gin): 16 VGPR
  float br[4], bz[4], bin[4], bhn[4];
  #pragma unroll
  for (int g = 0; g < 4; ++g) {
    const int c = g*16 + n16;
    br [g] = (b_ih[c]      + b_hh[c]     ) * NEG_LOG2E;
    bz [g] = (b_ih[64 + c] + b_hh[64 + c]) * NEG_LOG2E;
    bin[g] =  b_ih[128 + c]                * TWO_LOG2E;
    bhn[g] =  b_hh[128 + c]                * TWO_LOG2E;
  }
  const float b1v0 = b1[n16], b1v1 = b1[16 + n16];
  const float b2ln = (n16 < 4) ? b2[n16] : 0.f;

  __syncthreads();  // only barrier

  __bf16* const us = ubuf + wave*1152;   // this wave's slot
  bf16x8 a0 = *(const bf16x8*)&us[n16*72 + quad*8];
  bf16x8 a1 = *(const bf16x8*)&us[n16*72 + 32 + quad*8];

  // epilogue: 32 lanes, comp = lane>>4, row = lane&15
  const int erl  = lane & 15;            // epilogue local row
  const int comp = (lane >> 4) & 1;
  const float* xp = x + (size_t)(gb + wave*16 + erl)*(TT*2) + comp;
  float*       yp = y_out + (size_t)(gb + wave*16 + erl)*(TT*2) + comp;
  float yc = 0.f, prodS = 1.0f;

  #pragma unroll 1
  for (int t = 0; t < TT; ++t) {
    const float xt = (lane < 32) ? xp[t*2] : 0.f;   // issue global load early
    // y_{t-1} via shuffle from epilogue lanes (lane r: y[r][0]; lane 16+r: y[r][1])
    float ys0[4], ys1[4];
    #pragma unroll
    for (int i = 0; i < 4; ++i) {
      ys0[i] = __shfl(yc, quad*4 + i, 64);
      ys1[i] = __shfl(yc, 16 + quad*4 + i, 64);
    }

    // ---- GRU per col-group g (all pre-activations in scaled domain) ----
    #pragma unroll
    for (int g = 0; g < 4; ++g) {
      const bf16x8 bz0 = *(const bf16x8*)&whhtab[((g*2    )*64 + lane)*8];
      const bf16x8 bz1 = *(const bf16x8*)&whhtab[((g*2 + 1)*64 + lane)*8];
      const bf16x8 bn0 = *(const bf16x8*)&whhtab[((8 + g*2    )*64 + lane)*8];
      const bf16x8 bn1 = *(const bf16x8*)&whhtab[((8 + g*2 + 1)*64 + lane)*8];
      const float2 Tr = giw[      g*16 + n16];
      const float2 Tz = giw[ 64 + g*16 + n16];
      const float2 Tn = giw[128 + g*16 + n16];
      const f32x4 crinit = {br[g], br[g], br[g], br[g]};
      const f32x4 czinit = {bz[g], bz[g], bz[g], bz[g]};
      const f32x4 cninit = {bhn[g], bhn[g], bhn[g], bhn[g]};
      f32x4 cr = MFMA(a0, Whr[g][0], crinit); cr = MFMA(a1, Whr[g][1], cr);
      f32x4 cz = MFMA(a0, bz0, czinit);       cz = MFMA(a1, bz1, cz);
      f32x4 cn = MFMA(a0, bn0, cninit);       cn = MFMA(a1, bn1, cn);
      #pragma unroll
      for (int i = 0; i < 4; ++i) {
        const float sr  = fmaf(Tr.x, ys0[i], Tr.y*ys1[i]) + cr[i];            // = -log2e*vr
        const float sz  = fminf(fmaf(Tz.x, ys0[i], Tz.y*ys1[i]) + cz[i], 61.f);
        const float gin = fmaf(Tn.x, ys0[i], fmaf(Tn.y, ys1[i], bin[g]));     // = 2log2e*(..)
        const float r   = rcp_f(1.0f + exp2_f(sr));                           // sigmoid(vr)
        const float pre = fminf(fmaf(r, cn[i], gin), 61.f);                   // = 2log2e*vn
        // fused tail: u = 1/(1+Ez), tanh = (S-2)/S; hv = [h*S + Ez*(S-2)]/[S*(Ez+1)]
        const float Ez  = exp2_f(sz);
        const float En  = exp2_f(pre);
        const float S   = En + 1.0f;
        const float num = fmaf(S, hst[g][i] + Ez, Ez * -2.0f);
        const float den = fmaf(S, Ez, S);
        const float hv  = num * rcp_f(den);
        hst[g][i] = hv;
        us[(quad*4 + i)*72 + g*16 + n16] = (__bf16)hv;
      }
    }

    a0 = *(const bf16x8*)&us[n16*72 + quad*8];
    a1 = *(const bf16x8*)&us[n16*72 + 32 + quad*8];
    // h region now dead (held in a0/a1 + hst); slot reused as hid/ls below.

    // ---- MLP1 (hid: stride 40 within slot) ----
    #pragma unroll
    for (int c2 = 0; c2 < 2; ++c2) {
      const float bb = c2 ? b1v1 : b1v0;
      const f32x4 binit = {bb, bb, bb, bb};
      f32x4 hc = MFMA(a0, *(const bf16x8*)&w1tab[((c2*2  )*64 + lane)*8], binit);
      hc       = MFMA(a1, *(const bf16x8*)&w1tab[((c2*2+1)*64 + lane)*8], hc);
      #pragma unroll
      for (int i = 0; i < 4; ++i)
        us[(quad*4 + i)*40 + c2*16 + n16] = (__bf16)fmaxf(hc[i], 0.f);
    }

    // ---- MLP2: ls -> slot cols 32..39 (4 floats) ----
    {
      const bf16x8 ha = *(const bf16x8*)&us[n16*40 + quad*8];
      const f32x4 b2init = {b2ln, b2ln, b2ln, b2ln};
      const f32x4 ls = MFMA(ha, W2f, b2init);
      if (n16 < 4) {
        #pragma unroll
        for (int i = 0; i < 4; ++i)
          ((float*)&us[(quad*4 + i)*40 + 32])[n16] = ls[i];
      }
    }

    // ---- epilogue (32 lanes): y update + scale product (log deferred) ----
    if (lane < 32) {
      const float4 lsv = *(const float4*)&us[erl*40 + 32];
      const float lc = comp ? lsv.y : lsv.x;
      const float l2 = comp ? lsv.w : lsv.z;
      const float s  = __logf(1.0f + __expf(l2)) + 0.001f;
      yc += lc + s * xt;
      prodS *= s;
      yp[t*2] = yc;
    }
  }

  // logabsdet = log(prod_t s_t) per comp, summed over comps (matches reference)
  const float ll  = __logf(prodS);
  const float llo = __shfl(ll, lane ^ 16, 64);
  if (lane < 16) lad_out[gb + wave*16 + lane] = ll + llo;
}

extern "C" void kernel_launch(void* const* d_in, const int* in_sizes, int n_in,
                              void* d_out, int out_size, void* d_ws, size_t ws_size,
                              hipStream_t stream) {
  const float* x    = (const float*)d_in[0];
  const float* z    = (const float*)d_in[1];
  const float* W_ih = (const float*)d_in[2];
  const float* W_hh = (const float*)d_in[3];
  const float* b_ih = (const float*)d_in[4];
  const float* b_hh = (const float*)d_in[5];
  const float* W1   = (const float*)d_in[6];
  const float* b1   = (const float*)d_in[7];
  const float* W2   = (const float*)d_in[8];
  const float* b2   = (const float*)d_in[9];

  float* y_out   = (float*)d_out;
  float* lad_out = y_out + (size_t)BSZ * TT * 2;

  dim3 grid(BSZ / RPB), block(BLK);
  hipLaunchKernelGGL(flow13, grid, block, 0, stream,
                     x, z, W_ih, W_hh, b_ih, b_hh, W1, b1, W2, b2,
                     y_out, lad_out);
}

// Round 9
// 273.957 us; speedup vs baseline: 1.4579x; 1.4579x over previous
//
#include <hip/hip_runtime.h>

// B=131072, T=16, D=2, H=64. 16 rows/wave, 4 waves/block.
// R14 (from R13 post-mortem): R13's 541MB FETCH = local-mem demotion of the
// NEW shfl-fed ys arrays (only dataflow not matching a proven pattern; bias
// arrays mirror R9's proven bhn[4]). R14 keeps R13's LDS wins, drops the shfl:
//   - ubuf union (h stride-72 / hid stride-40 per-wave slot)  [R13-proven]
//   - giw float2 + biases hoisted to regs                     [bhn[4] pattern]
//   - ystate BACK in LDS, R9's exact float2-read epilogue     [R9-proven]
// LDS = 16384+4096+9216+1536+512 = 31744 B; x5 = 158720 <= 163840
//   -> 5 blocks/CU = 20 waves/CU (vs R9's 16). VGPR est ~95 <= 102 (5/SIMD).
// launch_bounds(256,3) cap 170 -- no tight caps (R6/R10/R11 lessons).
// Hot-loop numerics identical to R9 (fused single-rcp tail, deferred log).
#define BSZ 131072
#define TT  16
#define RPB 64
#define BLK 256

#define NEG_LOG2E  (-1.4426950408889634f)
#define TWO_LOG2E  2.8853900817779268f

typedef __bf16 bf16x8 __attribute__((ext_vector_type(8)));
typedef float  f32x4  __attribute__((ext_vector_type(4)));

#define MFMA(a,b,c) __builtin_amdgcn_mfma_f32_16x16x32_bf16((a),(b),(c),0,0,0)

static __device__ __forceinline__ float rcp_f(float v){ float r; asm("v_rcp_f32 %0, %1" : "=v"(r) : "v"(v)); return r; }
static __device__ __forceinline__ float exp2_f(float v){ float r; asm("v_exp_f32 %0, %1" : "=v"(r) : "v"(v)); return r; }

__global__ __launch_bounds__(BLK, 3) void flow14(
    const float* __restrict__ x,     // (B,16,2)
    const float* __restrict__ z,     // (B,64)
    const float* __restrict__ W_ih,  // (192,2)
    const float* __restrict__ W_hh,  // (192,64)
    const float* __restrict__ b_ih,  // (192)
    const float* __restrict__ b_hh,  // (192)
    const float* __restrict__ W1,    // (64,32)
    const float* __restrict__ b1,    // (32)
    const float* __restrict__ W2,    // (32,4)
    const float* __restrict__ b2,    // (4)
    float* __restrict__ y_out,       // (B,16,2)
    float* __restrict__ lad_out)     // (B)
{
  // LDS: 16384 + 4096 + 9216 + 1536 + 512 = 31744 B -> 5 blocks/CU
  __shared__ __align__(16) __bf16 whhtab[16*64*8];  // z/n-gate B-frags (pre-scaled)
  __shared__ __align__(16) __bf16 w1tab[4*64*8];    // W1 B-frags
  __shared__ __align__(16) __bf16 ubuf[RPB*72];     // per-wave 1152-elem slot:
                                                    //  h (stride 72), then hid/ls (stride 40)
  __shared__ __align__(16) float2 giw[192];         // {Wih0, Wih1} pre-scaled
  __shared__ __align__(16) float  ystate[RPB*2];    // y_{t-1} [row][comp]

  const int tid  = threadIdx.x;
  const int lane = tid & 63, wave = tid >> 6;
  const int quad = lane >> 4, n16 = lane & 15;
  const int gb   = blockIdx.x * RPB;
  const f32x4 zero = {0.f,0.f,0.f,0.f};

  // ---------- one-time staging ----------
  if (tid < 192) {  // giw: pre-scaled W_ih pairs
    const int j = tid;
    const float sc = (j < 128) ? NEG_LOG2E : TWO_LOG2E;
    giw[j] = make_float2(W_ih[2*j]*sc, W_ih[2*j+1]*sc);
  }
  // whhtab: f = (gate-1)*8 + g*2 + kt, gate 1=z (x -log2e), 2=n (x 2log2e)
  #pragma unroll
  for (int i = 0; i < 4; ++i) {
    const int f = i*4 + wave;
    const int gate = 1 + (f >> 3), g = (f >> 1) & 3, kt = f & 1;
    const float sc = (gate == 1) ? NEG_LOG2E : TWO_LOG2E;
    const float* p = W_hh + (size_t)((gate*4 + g)*16 + n16)*64 + kt*32 + quad*8;
    bf16x8 v;
    #pragma unroll
    for (int j = 0; j < 8; ++j) v[j] = (__bf16)(p[j]*sc);
    *(bf16x8*)&whhtab[(f*64 + lane)*8] = v;
  }
  { // w1tab: frag f = c2*2+kt, one per wave (unscaled)
    const int f = wave, c2 = f >> 1, kt = f & 1;
    bf16x8 v;
    #pragma unroll
    for (int j = 0; j < 8; ++j)
      v[j] = (__bf16)W1[(size_t)(kt*32 + quad*8 + j)*32 + c2*16 + n16];
    *(bf16x8*)&w1tab[(f*64 + lane)*8] = v;
  }
  if (tid < 128) ystate[tid] = 0.f;
  #pragma unroll
  for (int r4 = 0; r4 < 4; ++r4) {  // z -> ubuf h-regions (row*72 == slot layout)
    const int row = (tid >> 4) + r4*16, col = (tid & 15)*4;
    const float4 zv = *(const float4*)&z[(size_t)(gb + row)*64 + col];
    ubuf[row*72 + col+0] = (__bf16)zv.x; ubuf[row*72 + col+1] = (__bf16)zv.y;
    ubuf[row*72 + col+2] = (__bf16)zv.z; ubuf[row*72 + col+3] = (__bf16)zv.w;
  }

  // r-gate B-frags in regs (pre-scaled by -log2e): 8 x bf16x8 = 32 VGPR
  bf16x8 Whr[4][2];
  #pragma unroll
  for (int g = 0; g < 4; ++g)
    #pragma unroll
    for (int kt = 0; kt < 2; ++kt) {
      const float* p = W_hh + (size_t)(g*16 + n16)*64 + kt*32 + quad*8;
      bf16x8 v;
      #pragma unroll
      for (int j = 0; j < 8; ++j) v[j] = (__bf16)(p[j]*NEG_LOG2E);
      Whr[g][kt] = v;
    }
  // W2 B-frag in regs (4 VGPR)
  bf16x8 W2f;
  #pragma unroll
  for (int j = 0; j < 8; ++j)
    W2f[j] = (n16 < 4) ? (__bf16)W2[(size_t)(quad*8 + j)*4 + n16] : (__bf16)0.f;

  // h state fp32 C-layout: hst[g][i] = h[quad*4+i][g*16+n16]
  f32x4 hst[4];
  #pragma unroll
  for (int g = 0; g < 4; ++g)
    #pragma unroll
    for (int i = 0; i < 4; ++i)
      hst[g][i] = z[(size_t)(gb + wave*16 + quad*4 + i)*64 + g*16 + n16];
  // hoisted scaled biases (R9's proven bhn[4] pattern, extended): 16 VGPR
  float br[4], bz[4], bin[4], bhn[4];
  #pragma unroll
  for (int g = 0; g < 4; ++g) {
    const int c = g*16 + n16;
    br [g] = (b_ih[c]      + b_hh[c]     ) * NEG_LOG2E;
    bz [g] = (b_ih[64 + c] + b_hh[64 + c]) * NEG_LOG2E;
    bin[g] =  b_ih[128 + c]                * TWO_LOG2E;
    bhn[g] =  b_hh[128 + c]                * TWO_LOG2E;
  }
  const float b1v0 = b1[n16], b1v1 = b1[16 + n16];
  const float b2ln = (n16 < 4) ? b2[n16] : 0.f;

  __syncthreads();  // only barrier

  __bf16* const us = ubuf + wave*1152;   // this wave's slot
  bf16x8 a0 = *(const bf16x8*)&us[n16*72 + quad*8];
  bf16x8 a1 = *(const bf16x8*)&us[n16*72 + 32 + quad*8];

  // epilogue: 32 lanes, comp = lane>>4, row = lane&15
  const int erl  = lane & 15;
  const int comp = (lane >> 4) & 1;
  const int erow = wave*16 + erl;
  const float* xp = x + (size_t)(gb + erow)*(TT*2) + comp;
  float*       yp = y_out + (size_t)(gb + erow)*(TT*2) + comp;
  float yc = 0.f, prodS = 1.0f;

  #pragma unroll 1
  for (int t = 0; t < TT; ++t) {
    const float xt = (lane < 32) ? xp[t*2] : 0.f;   // issue global load early
    float ys0[4], ys1[4];
    #pragma unroll
    for (int i = 0; i < 4; ++i) {
      const float2 yv = *(const float2*)&ystate[(wave*16 + quad*4 + i)*2];
      ys0[i] = yv.x; ys1[i] = yv.y;
    }

    // ---- GRU per col-group g (all pre-activations in scaled domain) ----
    #pragma unroll
    for (int g = 0; g < 4; ++g) {
      const bf16x8 bz0 = *(const bf16x8*)&whhtab[((g*2    )*64 + lane)*8];
      const bf16x8 bz1 = *(const bf16x8*)&whhtab[((g*2 + 1)*64 + lane)*8];
      const bf16x8 bn0 = *(const bf16x8*)&whhtab[((8 + g*2    )*64 + lane)*8];
      const bf16x8 bn1 = *(const bf16x8*)&whhtab[((8 + g*2 + 1)*64 + lane)*8];
      f32x4 cr = MFMA(a0, Whr[g][0], zero); cr = MFMA(a1, Whr[g][1], cr);
      f32x4 cz = MFMA(a0, bz0, zero);       cz = MFMA(a1, bz1, cz);
      const f32x4 cninit = {bhn[g], bhn[g], bhn[g], bhn[g]};
      f32x4 cn = MFMA(a0, bn0, cninit);     cn = MFMA(a1, bn1, cn);
      const float2 Tr = giw[      g*16 + n16];
      const float2 Tz = giw[ 64 + g*16 + n16];
      const float2 Tn = giw[128 + g*16 + n16];
      #pragma unroll
      for (int i = 0; i < 4; ++i) {
        const float sr  = fmaf(Tr.x, ys0[i], fmaf(Tr.y, ys1[i], br[g])) + cr[i]; // = -log2e*vr
        const float sz  = fminf(fmaf(Tz.x, ys0[i], fmaf(Tz.y, ys1[i], bz[g])) + cz[i], 61.f);
        const float gin = fmaf(Tn.x, ys0[i], fmaf(Tn.y, ys1[i], bin[g]));        // = 2log2e*(..)
        const float r   = rcp_f(1.0f + exp2_f(sr));                              // sigmoid(vr)
        const float pre = fminf(fmaf(r, cn[i], gin), 61.f);                      // = 2log2e*vn
        // fused tail: u = 1/(1+Ez), tanh = (S-2)/S; hv = [h*S + Ez*(S-2)]/[S*(Ez+1)]
        const float Ez  = exp2_f(sz);
        const float En  = exp2_f(pre);
        const float S   = En + 1.0f;
        const float num = fmaf(S, hst[g][i] + Ez, Ez * -2.0f);
        const float den = fmaf(S, Ez, S);
        const float hv  = num * rcp_f(den);
        hst[g][i] = hv;
        us[(quad*4 + i)*72 + g*16 + n16] = (__bf16)hv;
      }
    }

    a0 = *(const bf16x8*)&us[n16*72 + quad*8];
    a1 = *(const bf16x8*)&us[n16*72 + 32 + quad*8];
    // h region dead from here (held in a0/a1 + hst); slot reused as hid/ls.

    // ---- MLP1 (hid: stride 40 within slot) ----
    #pragma unroll
    for (int c2 = 0; c2 < 2; ++c2) {
      const float bb = c2 ? b1v1 : b1v0;
      const f32x4 binit = {bb, bb, bb, bb};
      f32x4 hc = MFMA(a0, *(const bf16x8*)&w1tab[((c2*2  )*64 + lane)*8], binit);
      hc       = MFMA(a1, *(const bf16x8*)&w1tab[((c2*2+1)*64 + lane)*8], hc);
      #pragma unroll
      for (int i = 0; i < 4; ++i)
        us[(quad*4 + i)*40 + c2*16 + n16] = (__bf16)fmaxf(hc[i], 0.f);
    }

    // ---- MLP2: ls -> slot cols 32..39 (4 floats) ----
    {
      const bf16x8 ha = *(const bf16x8*)&us[n16*40 + quad*8];
      const f32x4 b2init = {b2ln, b2ln, b2ln, b2ln};
      const f32x4 ls = MFMA(ha, W2f, b2init);
      if (n16 < 4) {
        #pragma unroll
        for (int i = 0; i < 4; ++i)
          ((float*)&us[(quad*4 + i)*40 + 32])[n16] = ls[i];
      }
    }

    // ---- epilogue (32 lanes): y update + scale product (log deferred) ----
    if (lane < 32) {
      const float* lsp = (const float*)&us[erl*40 + 32];
      const float lc = lsp[comp];
      const float l2 = lsp[2 + comp];
      const float s  = __logf(1.0f + __expf(l2)) + 0.001f;
      yc += lc + s * xt;
      prodS *= s;
      ystate[erow*2 + comp] = yc;
      yp[t*2] = yc;
    }
  }

  // logabsdet = log(prod_t s_t) per comp, summed over comps (matches reference)
  const float ll  = __logf(prodS);
  const float llo = __shfl(ll, lane ^ 16, 64);
  if (lane < 16) lad_out[gb + wave*16 + lane] = ll + llo;
}

extern "C" void kernel_launch(void* const* d_in, const int* in_sizes, int n_in,
                              void* d_out, int out_size, void* d_ws, size_t ws_size,
                              hipStream_t stream) {
  const float* x    = (const float*)d_in[0];
  const float* z    = (const float*)d_in[1];
  const float* W_ih = (const float*)d_in[2];
  const float* W_hh = (const float*)d_in[3];
  const float* b_ih = (const float*)d_in[4];
  const float* b_hh = (const float*)d_in[5];
  const float* W1   = (const float*)d_in[6];
  const float* b1   = (const float*)d_in[7];
  const float* W2   = (const float*)d_in[8];
  const float* b2   = (const float*)d_in[9];

  float* y_out   = (float*)d_out;
  float* lad_out = y_out + (size_t)BSZ * TT * 2;

  dim3 grid(BSZ / RPB), block(BLK);
  hipLaunchKernelGGL(flow14, grid, block, 0, stream,
                     x, z, W_ih, W_hh, b_ih, b_hh, W1, b1, W2, b2,
                     y_out, lad_out);
}